// Round 4
// baseline (196.248 us; speedup 1.0000x reference)
//
#include <hip/hip_runtime.h>
#include <math.h>

#define N_NODES 100000
#define N_EDGES 3200000
#define EPS_F 1e-6f
#define PAIRS   (N_EDGES / 2)           // 1,600,000

// ---- prep geometry: 256 thr x 2 pairs = 512 pairs/block ----
#define PPT        2
#define PREP_T     256
#define PREP_PAIRS (PREP_T * PPT)       // 512
#define NPREPB     (PAIRS / PREP_PAIRS) // 3125 (exact)
#define LCAP       512                  // LDS list cap per slice (mean 256 + 17 sigma)

// ---- chunk/slice geometry ----
#define NCHUNK  25                      // divides 3125 -> 125 prep blocks/chunk
#define NSLICE  8
#define SLICE_N 12500                   // 8*12500 = 100000
#define PB_PER_CHUNK (NPREPB / NCHUNK)  // 125
#define BCAP    49152                   // bucket cap (mean 32000 + ~100 sigma)
#define NBUCK   (NCHUNK * NSLICE)       // 200

#define NKCLB   391                     // ceil(100000/256)

// ws layout (4-byte words) — ~49.4 MB (<= proven 51.3 MB budget)
//   CTR      : u32 bucket counters[200] + done-counter (zeroed by 1KB memset)
//   BUCK     : u32 entries[NBUCK][BCAP]  entry = curbf<<16 | neg<<14 | local_id
//   PART     : partials[NCHUNK=25][N_NODES]  (10 MB)
//   VARP     : per-prep-block float4 {s0,s1,q0,q1}[NPREPB]
//   KCLP     : per-block kcl partial [NKCLB]
// Each endpoint is routed to its ONE slice at prep time: scatter reads each
// entry exactly once (26 MB) instead of re-scanning all records 8x (205 MB).
#define CTR_OFF   0
#define CNT_WORD  200
#define BUCK_OFF  256
#define PART_OFF  (BUCK_OFF + NBUCK * BCAP)       // 9,830,656
#define VARP_OFF  (PART_OFF + NCHUNK * N_NODES)   // 12,330,656
#define KCLP_OFF  (VARP_OFF + 4 * NPREPB)
#define WS_FLOATS (KCLP_OFF + NKCLB + 64)

__device__ __forceinline__ float wave_reduce(float v) {
    #pragma unroll
    for (int off = 32; off > 0; off >>= 1) v += __shfl_down(v, off, 64);
    return v;
}

__device__ __forceinline__ void fadd_agent(float* p, float v) {
    unsafeAtomicAdd(p, v);   // fallback path only
}

// bf16 pack/unpack (RNE)
__device__ __forceinline__ unsigned short f2bf(float f) {
    unsigned u = __float_as_uint(f);
    unsigned r = ((u >> 16) & 1u) + 0x7FFFu;
    return (unsigned short)((u + r) >> 16);
}
__device__ __forceinline__ float bf2f(unsigned short h) {
    return __uint_as_float(((unsigned)h) << 16);
}

// ---------------- pass 1: prep = decode + cur + slice-route into buckets + varsum ----------------
__global__ __launch_bounds__(256) void prep_kernel(
    const float*  __restrict__ nf,
    const void*   __restrict__ eidx,
    const float*  __restrict__ logits,
    const float2* __restrict__ params,
    float*        __restrict__ ws)
{
    __shared__ unsigned lists[NSLICE][LCAP];   // 16 KB
    __shared__ unsigned lcnt[NSLICE];
    __shared__ unsigned lbase[NSLICE];
    __shared__ float    red[4][4];

    const int* i32 = (const int*)eidx;

    // int64 values < 2^31 have zero hi-words at every odd int32 slot;
    // int32 has random node ids there (16 zeros ~ impossible).
    int any = 0;
    #pragma unroll
    for (int k = 1; k < 32; k += 2) any |= i32[k];
    const bool is32 = (any != 0);

    if (threadIdx.x < NSLICE) lcnt[threadIdx.x] = 0;
    __syncthreads();

    const int t0 = blockIdx.x * PREP_PAIRS + threadIdx.x;   // pair A
    const int t1 = t0 + PREP_T;                             // pair B
    const int chunk = blockIdx.x / PB_PER_CHUNK;

    unsigned* gctr = (unsigned*)ws + CTR_OFF;
    unsigned* buck = (unsigned*)(ws + BUCK_OFF);

    int2 sp0, dp0, sp1, dp1;
    if (is32) {
        sp0 = ((const int2*)i32)[t0];
        sp1 = ((const int2*)i32)[t1];
        dp0 = ((const int2*)(i32 + N_EDGES))[t0];
        dp1 = ((const int2*)(i32 + N_EDGES))[t1];
    } else {
        const int4 a0 = ((const int4*)i32)[t0];
        const int4 a1 = ((const int4*)i32)[t1];
        const int4 b0 = ((const int4*)(i32 + 2 * N_EDGES))[t0];
        const int4 b1 = ((const int4*)(i32 + 2 * N_EDGES))[t1];
        sp0 = make_int2(a0.x, a0.z);  sp1 = make_int2(a1.x, a1.z);
        dp0 = make_int2(b0.x, b0.z);  dp1 = make_int2(b1.x, b1.z);
    }

    // 8 independent random 4B reads from the 1.6 MB (L2-resident) nf table
    const float vs00 = nf[sp0.x * 4];
    const float vd00 = nf[dp0.x * 4];
    const float vs01 = nf[sp0.y * 4];
    const float vd01 = nf[dp0.y * 4];
    const float vs10 = nf[sp1.x * 4];
    const float vd10 = nf[dp1.x * 4];
    const float vs11 = nf[sp1.y * 4];
    const float vd11 = nf[dp1.y * 4];

    const float4 pp0 = ((const float4*)params)[t0];
    const float4 pp1 = ((const float4*)params)[t1];
    const float2 lg0 = ((const float2*)logits)[t0];
    const float2 lg1 = ((const float2*)logits)[t1];

    const float w00 = (1.0f / (1.0f + __expf(-lg0.x))) / (pp0.x + pp0.y + EPS_F);
    const float w01 = (1.0f / (1.0f + __expf(-lg0.y))) / (pp0.z + pp0.w + EPS_F);
    const float w10 = (1.0f / (1.0f + __expf(-lg1.x))) / (pp1.x + pp1.y + EPS_F);
    const float w11 = (1.0f / (1.0f + __expf(-lg1.y))) / (pp1.z + pp1.w + EPS_F);

    const unsigned cb00 = f2bf(fabsf(vs00 - vd00) * w00);
    const unsigned cb01 = f2bf(fabsf(vs01 - vd01) * w01);
    const unsigned cb10 = f2bf(fabsf(vs10 - vd10) * w10);
    const unsigned cb11 = f2bf(fabsf(vs11 - vd11) * w11);

    // route each endpoint to its slice; dst gets +cur (neg=0), src gets -cur (neg=1)
    #define APPEND(id, curbf, neg) do {                                        \
        const unsigned s_  = (unsigned)(id) / SLICE_N;                         \
        const unsigned e_  = ((curbf) << 16) | ((neg) << 14)                   \
                             | ((unsigned)(id) - s_ * SLICE_N);                \
        const unsigned ix_ = atomicAdd(&lcnt[s_], 1u);                         \
        if (ix_ < LCAP) lists[s_][ix_] = e_;                                   \
        else {  /* correct slow path, statistically never taken */             \
            const unsigned g_ = atomicAdd(&gctr[chunk * NSLICE + s_], 1u);     \
            if (g_ < BCAP) buck[(chunk * NSLICE + s_) * BCAP + g_] = e_;       \
        }                                                                      \
    } while (0)

    APPEND(dp0.x, cb00, 0u);  APPEND(sp0.x, cb00, 1u);
    APPEND(dp0.y, cb01, 0u);  APPEND(sp0.y, cb01, 1u);
    APPEND(dp1.x, cb10, 0u);  APPEND(sp1.x, cb10, 1u);
    APPEND(dp1.y, cb11, 0u);  APPEND(sp1.y, cb11, 1u);
    #undef APPEND

    __syncthreads();
    if (threadIdx.x < NSLICE) {
        unsigned n = lcnt[threadIdx.x];
        if (n > LCAP) n = LCAP;
        lcnt[threadIdx.x]  = n;
        lbase[threadIdx.x] = atomicAdd(&gctr[chunk * NSLICE + threadIdx.x], n);
    }
    __syncthreads();

    // coalesced flush of the 8 lists to their bucket segments
    #pragma unroll
    for (int s = 0; s < NSLICE; ++s) {
        const unsigned n = lcnt[s], b = lbase[s];
        unsigned* seg = buck + (chunk * NSLICE + s) * BCAP;
        for (unsigned j = threadIdx.x; j < n; j += PREP_T) {
            const unsigned slot = b + j;
            if (slot < BCAP) seg[slot] = lists[s][j];
        }
    }

    // variance partials (both pairs)
    float s0 = pp0.x + pp0.z + pp1.x + pp1.z;
    float s1 = pp0.y + pp0.w + pp1.y + pp1.w;
    float q0 = pp0.x * pp0.x + pp0.z * pp0.z + pp1.x * pp1.x + pp1.z * pp1.z;
    float q1 = pp0.y * pp0.y + pp0.w * pp0.w + pp1.y * pp1.y + pp1.w * pp1.w;

    s0 = wave_reduce(s0); s1 = wave_reduce(s1);
    q0 = wave_reduce(q0); q1 = wave_reduce(q1);

    const int wid = threadIdx.x >> 6;
    if ((threadIdx.x & 63) == 0) {
        red[wid][0] = s0; red[wid][1] = s1; red[wid][2] = q0; red[wid][3] = q1;
    }
    __syncthreads();
    if (threadIdx.x == 0) {
        float4 o;
        o.x = red[0][0] + red[1][0] + red[2][0] + red[3][0];
        o.y = red[0][1] + red[1][1] + red[2][1] + red[3][1];
        o.z = red[0][2] + red[1][2] + red[2][2] + red[3][2];
        o.w = red[0][3] + red[1][3] + red[2][3] + red[3][3];
        ((float4*)(ws + VARP_OFF))[blockIdx.x] = o;
    }
}

// ---------------- pass 2: one-shot binned scatter (each entry read exactly once) ----------------
__global__ __launch_bounds__(1024) void scatter_kernel(float* __restrict__ ws)
{
    __shared__ float bins[SLICE_N];   // 50,000 B

    const int c = blockIdx.x >> 3;
    const int s = blockIdx.x & 7;

    const unsigned* gctr = (const unsigned*)ws + CTR_OFF;
    unsigned cnt = gctr[c * NSLICE + s];
    if (cnt > BCAP) cnt = BCAP;
    const unsigned* seg = (const unsigned*)(ws + BUCK_OFF) + (size_t)(c * NSLICE + s) * BCAP;

    for (int j = threadIdx.x; j < SLICE_N; j += 1024) bins[j] = 0.f;
    __syncthreads();

    for (unsigned base = threadIdx.x; base < cnt; base += 1024u * 8u) {
        unsigned q[8];
        #pragma unroll
        for (int k = 0; k < 8; ++k) {
            unsigned p = base + (unsigned)k * 1024u;
            p = (p < cnt) ? p : (cnt - 1u);   // clamp: loads stay unconditional
            q[k] = seg[p];
        }
        #pragma unroll
        for (int k = 0; k < 8; ++k) {
            const unsigned p = base + (unsigned)k * 1024u;
            if (p < cnt) {
                const unsigned e = q[k];
                // bits31:16 = bf16 cur ; bit14 = sign ; bits13:0 = local id
                const float v = __uint_as_float((e & 0xFFFF0000u) ^ ((e << 17) & 0x80000000u));
                atomicAdd(&bins[e & 0x3FFFu], v);
            }
        }
    }
    __syncthreads();

    float4* pt4 = (float4*)(ws + PART_OFF + (size_t)c * N_NODES + s * SLICE_N);
    for (int j = threadIdx.x; j < SLICE_N / 4; j += 1024)
        pt4[j] = ((const float4*)bins)[j];
}

// ---------------- pass 3: merge partials + squares; LAST block folds final ----------------
__global__ __launch_bounds__(256) void kclfinal_kernel(float* __restrict__ ws,
                                                       float* __restrict__ out)
{
    __shared__ float red[4];
    __shared__ unsigned last;

    const int i = blockIdx.x * blockDim.x + threadIdx.x;
    float acc = 0.f;
    if (i < N_NODES) {
        const float* p = ws + PART_OFF + i;
        float s = 0.f;
        #pragma unroll 5
        for (int c = 0; c < NCHUNK; ++c) s += p[(size_t)c * N_NODES];
        acc = s * s;
    }
    acc = wave_reduce(acc);
    if ((threadIdx.x & 63) == 0) red[threadIdx.x >> 6] = acc;
    __syncthreads();
    if (threadIdx.x == 0) {
        ws[KCLP_OFF + blockIdx.x] = red[0] + red[1] + red[2] + red[3];
        __threadfence();   // KCLP store visible before counter bump
        const unsigned old = atomicAdd((unsigned*)ws + CNT_WORD, 1u);
        last = (old == NKCLB - 1) ? 1u : 0u;
    }
    __syncthreads();
    if (!last) return;

    // ---- final reduction (one block, 256 threads) ----
    __shared__ float red2[4][5];
    float s0 = 0.f, s1 = 0.f, q0 = 0.f, q1 = 0.f, k = 0.f;

    const float4* vp = (const float4*)(ws + VARP_OFF);   // prep output: kernel-boundary safe
    for (int j = threadIdx.x; j < NPREPB; j += 256) {
        const float4 v = vp[j];
        s0 += v.x; s1 += v.y; q0 += v.z; q1 += v.w;
    }
    // KCLP written by other blocks this kernel: cross-XCD L2 not coherent ->
    // read via device-scope atomic RMW (+0.0 returns old value).
    for (int j = threadIdx.x; j < NKCLB; j += 256)
        k += unsafeAtomicAdd(ws + KCLP_OFF + j, 0.0f);

    s0 = wave_reduce(s0); s1 = wave_reduce(s1);
    q0 = wave_reduce(q0); q1 = wave_reduce(q1);
    k  = wave_reduce(k);

    const int wid = threadIdx.x >> 6;
    if ((threadIdx.x & 63) == 0) {
        red2[wid][0] = s0; red2[wid][1] = s1; red2[wid][2] = q0;
        red2[wid][3] = q1; red2[wid][4] = k;
    }
    __syncthreads();
    if (threadIdx.x == 0) {
        float a0 = 0.f, a1 = 0.f, a2 = 0.f, a3 = 0.f, a4 = 0.f;
        #pragma unroll
        for (int w = 0; w < 4; ++w) {
            a0 += red2[w][0]; a1 += red2[w][1]; a2 += red2[w][2];
            a3 += red2[w][3]; a4 += red2[w][4];
        }
        const float n    = (float)N_EDGES;
        const float var0 = (a2 - a0 * a0 / n) / (n - 1.0f);
        const float var1 = (a3 - a1 * a1 / n) / (n - 1.0f);
        out[0] = a4 / (float)N_NODES + 0.5f * (var0 + var1);
    }
}

// ---------------- fallback (ws too small): agent-atomic scatter ----------------
#define FB_NODE_OFF 64
__global__ __launch_bounds__(256) void edge_kernel_fb(
    const float*  __restrict__ nf,
    const void*   __restrict__ eidx,
    const float*  __restrict__ logits,
    const float2* __restrict__ params,
    float*        __restrict__ ws)
{
    const int*       i32 = (const int*)eidx;
    const long long* i64 = (const long long*)eidx;
    int any = 0;
    #pragma unroll
    for (int k = 1; k < 32; k += 2) any |= i32[k];
    const bool is32 = (any != 0);

    float* node_sum = ws + FB_NODE_OFF;
    float* acc      = ws + 1;

    float s0 = 0.f, s1 = 0.f, q0 = 0.f, q1 = 0.f;
    const int tid    = blockIdx.x * blockDim.x + threadIdx.x;
    const int stride = gridDim.x * blockDim.x;
    for (int i = tid; i < N_EDGES; i += stride) {
        int src, dst;
        if (is32) { src = i32[i]; dst = i32[N_EDGES + i]; }
        else      { src = (int)i64[i]; dst = (int)i64[N_EDGES + i]; }
        const float2 ep = params[i];
        const float  p  = 1.0f / (1.0f + __expf(-logits[i]));
        const float cur = fabsf(nf[src * 4] - nf[dst * 4]) / (ep.x + ep.y + EPS_F) * p;
        fadd_agent(node_sum + dst,  cur);
        fadd_agent(node_sum + src, -cur);
        s0 += ep.x; s1 += ep.y; q0 += ep.x * ep.x; q1 += ep.y * ep.y;
    }
    s0 = wave_reduce(s0); s1 = wave_reduce(s1);
    q0 = wave_reduce(q0); q1 = wave_reduce(q1);
    if ((threadIdx.x & 63) == 0) {
        fadd_agent(acc + 0, s0); fadd_agent(acc + 1, s1);
        fadd_agent(acc + 2, q0); fadd_agent(acc + 3, q1);
    }
}

__global__ __launch_bounds__(256) void kcl_kernel_fb(float* __restrict__ ws)
{
    const float* node_sum = ws + FB_NODE_OFF;
    float acc = 0.f;
    const int tid    = blockIdx.x * blockDim.x + threadIdx.x;
    const int stride = gridDim.x * blockDim.x;
    for (int i = tid; i < N_NODES; i += stride) {
        const float v = node_sum[i];
        acc += v * v;
    }
    acc = wave_reduce(acc);
    if ((threadIdx.x & 63) == 0) fadd_agent(ws + 5, acc);
}

__global__ void final_kernel_fb(const float* __restrict__ ws, float* __restrict__ out)
{
    const float s0 = ws[1], s1 = ws[2], q0 = ws[3], q1 = ws[4], k = ws[5];
    const float n  = (float)N_EDGES;
    const float var0 = (q0 - s0 * s0 / n) / (n - 1.0f);
    const float var1 = (q1 - s1 * s1 / n) / (n - 1.0f);
    out[0] = k / (float)N_NODES + 0.5f * (var0 + var1);
}

extern "C" void kernel_launch(void* const* d_in, const int* in_sizes, int n_in,
                              void* d_out, int out_size, void* d_ws, size_t ws_size,
                              hipStream_t stream) {
    const float*  nf     = (const float*)d_in[0];
    const void*   eidx   = d_in[1];
    const float*  logits = (const float*)d_in[2];
    const float2* params = (const float2*)d_in[3];
    float* ws  = (float*)d_ws;
    float* out = (float*)d_out;

    const size_t need = (size_t)WS_FLOATS * sizeof(float);   // ~49.4 MB

    if (ws_size >= need) {
        hipMemsetAsync(d_ws, 0, 1024, stream);   // bucket counters + done-counter
        prep_kernel<<<NPREPB, 256, 0, stream>>>(nf, eidx, logits, params, ws);
        scatter_kernel<<<NBUCK, 1024, 0, stream>>>(ws);
        kclfinal_kernel<<<NKCLB, 256, 0, stream>>>(ws, out);
    } else {
        hipMemsetAsync(d_ws, 0, 256 + (size_t)N_NODES * sizeof(float), stream);
        edge_kernel_fb<<<2048, 256, 0, stream>>>(nf, eidx, logits, params, ws);
        kcl_kernel_fb<<<200, 256, 0, stream>>>(ws);
        final_kernel_fb<<<1, 1, 0, stream>>>(ws, out);
    }
}

// Round 5
// 169.620 us; speedup vs baseline: 1.1570x; 1.1570x over previous
//
#include <hip/hip_runtime.h>
#include <math.h>

#define N_NODES 100000
#define N_EDGES 3200000
#define EPS_F 1e-6f
#define PAIRS   (N_EDGES / 2)           // 1,600,000

// ---- prep geometry: 256 blocks x 1024 thr, 160 KB bf16 v-table in LDS ----
#define TBL_N   80000                   // bf16 nodes in LDS (160,000 B); rest spill to L2
#define GNB     256
#define GSTRIDE (GNB * 1024)            // 262,144 threads
#define NVARW   (GNB * 16)              // per-wave varsum partials (4096)

// ---- scatter: EXACT R3 geometry (proven) ----
#define SLICE_N 12500                   // 8*12500 = 100000
#define NSLICE  8
#define NCHUNK  32
#define C_PAIRS (N_EDGES / 2 / NCHUNK)  // 50000 pairs per chunk
#define SBATCH  8

#define NKCLB   391                     // ceil(100000/256)
#define NPACKB  196                     // 50176 threads >= 50000

// ws layout (4-byte words) — ~38.7 MB
//   CNT_WORD : done-counter (reset by pack_kernel)
//   PK_OFF   : u64 pack[N_EDGES]  lo = src | dst<<17 ; hi = (dst>>15) | cur<<2
//   PART_OFF : partials[NCHUNK=32][N_NODES]  (12.8 MB)
//   VARP_OFF : per-WAVE float4 {s0,s1,q0,q1}[NVARW]
//   KCLP_OFF : per-block kcl partial [NKCLB]
//   VBF_OFF  : bf16 v[N_NODES] (packed by pack_kernel; table source + spill reads)
#define CNT_WORD  32
#define PK_OFF    64
#define PART_OFF  (PK_OFF + 2 * N_EDGES)          // 6,400,064
#define VARP_OFF  (PART_OFF + NCHUNK * N_NODES)   // 9,600,064
#define KCLP_OFF  (VARP_OFF + 4 * NVARW)          // 9,616,448
#define VBF_OFF   (KCLP_OFF + 512)                // 9,616,960 (aligned)
#define WS_FLOATS (VBF_OFF + N_NODES / 2 + 64)

__device__ __forceinline__ float wave_reduce(float v) {
    #pragma unroll
    for (int off = 32; off > 0; off >>= 1) v += __shfl_down(v, off, 64);
    return v;
}

__device__ __forceinline__ void fadd_agent(float* p, float v) {
    unsafeAtomicAdd(p, v);   // fallback path only
}

// bf16 pack/unpack (RNE)
__device__ __forceinline__ unsigned short f2bf(float f) {
    unsigned u = __float_as_uint(f);
    unsigned r = ((u >> 16) & 1u) + 0x7FFFu;
    return (unsigned short)((u + r) >> 16);
}
__device__ __forceinline__ float bf2f(unsigned short h) {
    return __uint_as_float(((unsigned)h) << 16);
}

// ---------------- pass 0: pack v to bf16 (once) + reset done-counter ----------------
__global__ __launch_bounds__(256) void pack_kernel(
    const float* __restrict__ nf, float* __restrict__ ws)
{
    const int t = blockIdx.x * 256 + threadIdx.x;
    if (t == 0) ((unsigned*)ws)[CNT_WORD] = 0;
    if (t < N_NODES / 2) {
        const float4 a = ((const float4*)nf)[2 * t];       // node 2t   (v = .x)
        const float4 b = ((const float4*)nf)[2 * t + 1];   // node 2t+1 (v = .x)
        ((unsigned*)(ws + VBF_OFF))[t] = (unsigned)f2bf(a.x) | ((unsigned)f2bf(b.x) << 16);
    }
}

// ---------------- pass 1: prep = LDS v-table gather + pack ids+cur + varsum ----------------
// 80000 bf16 nodes in 160,000 B LDS (80% hit, ~6 cy/lookup); spill ids read the
// bf16 global table (L2-resident, only ~20% of lanes active on that path).
// Per-wave varsum partials -> global (no LDS scratch, no append atomics).
__global__ __launch_bounds__(1024, 4) void prep_kernel(
    const void*   __restrict__ eidx,
    const float*  __restrict__ logits,
    const float2* __restrict__ params,
    float*        __restrict__ ws)
{
    __shared__ unsigned vlds[TBL_N / 2];   // 160,000 B

    // fill table (coalesced uint loads of packed bf16)
    const unsigned* vsrc = (const unsigned*)(ws + VBF_OFF);
    for (int j = threadIdx.x; j < TBL_N / 2; j += 1024) vlds[j] = vsrc[j];

    const int* i32 = (const int*)eidx;
    // int64 values < 2^31 have zero hi-words at every odd int32 slot;
    // int32 has random node ids there (16 zeros ~ impossible).
    int any = 0;
    #pragma unroll
    for (int k = 1; k < 32; k += 2) any |= i32[k];
    const bool is32 = (any != 0);

    __syncthreads();
    const unsigned short* vl = (const unsigned short*)vlds;
    const unsigned short* vg = (const unsigned short*)(ws + VBF_OFF);

    const int gtid = blockIdx.x * 1024 + threadIdx.x;
    int4* pk = (int4*)(ws + PK_OFF);

    float s0 = 0.f, s1 = 0.f, q0 = 0.f, q1 = 0.f;

    #define VGET(id) bf2f(((unsigned)(id) < TBL_N) ? vl[id] : vg[id])

    for (int p = gtid; p < PAIRS; p += 2 * GSTRIDE) {
        const int pb  = p + GSTRIDE;
        const int pbc = (pb < PAIRS) ? pb : p;   // clamp: loads stay unconditional

        int2 spA, dpA, spB, dpB;
        if (is32) {
            spA = ((const int2*)i32)[p];
            spB = ((const int2*)i32)[pbc];
            dpA = ((const int2*)(i32 + N_EDGES))[p];
            dpB = ((const int2*)(i32 + N_EDGES))[pbc];
        } else {
            const int4 a0 = ((const int4*)i32)[p];
            const int4 a1 = ((const int4*)i32)[pbc];
            const int4 b0 = ((const int4*)(i32 + 2 * N_EDGES))[p];
            const int4 b1 = ((const int4*)(i32 + 2 * N_EDGES))[pbc];
            spA = make_int2(a0.x, a0.z);  spB = make_int2(a1.x, a1.z);
            dpA = make_int2(b0.x, b0.z);  dpB = make_int2(b1.x, b1.z);
        }
        const float4 ppA = ((const float4*)params)[p];
        const float4 ppB = ((const float4*)params)[pbc];
        const float2 lgA = ((const float2*)logits)[p];
        const float2 lgB = ((const float2*)logits)[pbc];

        // 8 lookups: ~80% LDS (cheap), ~20% L2 bf16 spill
        const float vsA0 = VGET(spA.x), vdA0 = VGET(dpA.x);
        const float vsA1 = VGET(spA.y), vdA1 = VGET(dpA.y);
        const float vsB0 = VGET(spB.x), vdB0 = VGET(dpB.x);
        const float vsB1 = VGET(spB.y), vdB1 = VGET(dpB.y);

        const float wA0 = (1.0f / (1.0f + __expf(-lgA.x))) / (ppA.x + ppA.y + EPS_F);
        const float wA1 = (1.0f / (1.0f + __expf(-lgA.y))) / (ppA.z + ppA.w + EPS_F);
        const float wB0 = (1.0f / (1.0f + __expf(-lgB.x))) / (ppB.x + ppB.y + EPS_F);
        const float wB1 = (1.0f / (1.0f + __expf(-lgB.y))) / (ppB.z + ppB.w + EPS_F);

        const float cA0 = fabsf(vsA0 - vdA0) * wA0;
        const float cA1 = fabsf(vsA1 - vdA1) * wA1;
        const float cB0 = fabsf(vsB0 - vdB0) * wB0;
        const float cB1 = fabsf(vsB1 - vdB1) * wB1;

        int4 oA, oB;
        oA.x = (int)((unsigned)spA.x | ((unsigned)dpA.x << 17));
        oA.y = (int)((((unsigned)dpA.x) >> 15) | ((unsigned)f2bf(cA0) << 2));
        oA.z = (int)((unsigned)spA.y | ((unsigned)dpA.y << 17));
        oA.w = (int)((((unsigned)dpA.y) >> 15) | ((unsigned)f2bf(cA1) << 2));
        oB.x = (int)((unsigned)spB.x | ((unsigned)dpB.x << 17));
        oB.y = (int)((((unsigned)dpB.x) >> 15) | ((unsigned)f2bf(cB0) << 2));
        oB.z = (int)((unsigned)spB.y | ((unsigned)dpB.y << 17));
        oB.w = (int)((((unsigned)dpB.y) >> 15) | ((unsigned)f2bf(cB1) << 2));

        pk[p] = oA;
        s0 += ppA.x + ppA.z;  s1 += ppA.y + ppA.w;
        q0 += ppA.x * ppA.x + ppA.z * ppA.z;
        q1 += ppA.y * ppA.y + ppA.w * ppA.w;
        if (pb < PAIRS) {
            pk[pb] = oB;
            s0 += ppB.x + ppB.z;  s1 += ppB.y + ppB.w;
            q0 += ppB.x * ppB.x + ppB.z * ppB.z;
            q1 += ppB.y * ppB.y + ppB.w * ppB.w;
        }
    }
    #undef VGET

    s0 = wave_reduce(s0); s1 = wave_reduce(s1);
    q0 = wave_reduce(q0); q1 = wave_reduce(q1);

    if ((threadIdx.x & 63) == 0) {
        float4 o; o.x = s0; o.y = s1; o.z = q0; o.w = q1;
        ((float4*)(ws + VARP_OFF))[blockIdx.x * 16 + (threadIdx.x >> 6)] = o;
    }
}

// ---------------- pass 2: LDS-binned scatter — R3-proven schedule ----------------
// grid 256 (1 block/CU), 50K pairs/chunk -> 7 batched iterations, SBATCH=8 int4.
// Slice partners of chunk c: blockIdx = c + 32*s ≡ c (mod 8) -> same XCD;
// 4 chunks/XCD * 800 KB = 3.2 MB < 4 MB L2.
__global__ __launch_bounds__(1024) void scatter_kernel(float* __restrict__ ws)
{
    __shared__ float bins[SLICE_N];   // 50,000 B

    const int c  = blockIdx.x & (NCHUNK - 1);
    const int s  = blockIdx.x >> 5;
    const unsigned lo = (unsigned)(s * SLICE_N);

    for (int j = threadIdx.x; j < SLICE_N; j += 1024) bins[j] = 0.f;
    __syncthreads();

    const int4* pk = (const int4*)(ws + PK_OFF);

    const int p0 = c * C_PAIRS;
    const int p1 = p0 + C_PAIRS;

    for (int base = p0 + (int)threadIdx.x; base < p1; base += 1024 * SBATCH) {
        int4 q[SBATCH];
        #pragma unroll
        for (int k = 0; k < SBATCH; ++k) {
            int p = base + k * 1024;
            p = (p < p1) ? p : (p1 - 1);   // clamp: loads stay unconditional
            q[k] = pk[p];
        }
        #pragma unroll
        for (int k = 0; k < SBATCH; ++k) {
            const int p = base + k * 1024;
            if (p < p1) {
                const unsigned lo0 = (unsigned)q[k].x, hi0 = (unsigned)q[k].y;
                const unsigned lo1 = (unsigned)q[k].z, hi1 = (unsigned)q[k].w;
                const unsigned s0 = (lo0 & 0x1FFFFu) - lo;
                const unsigned d0 = ((lo0 >> 17) | ((hi0 & 3u) << 15)) - lo;
                const unsigned s1 = (lo1 & 0x1FFFFu) - lo;
                const unsigned d1 = ((lo1 >> 17) | ((hi1 & 3u) << 15)) - lo;
                const float c0 = bf2f((unsigned short)((hi0 >> 2) & 0xFFFFu));
                const float c1 = bf2f((unsigned short)((hi1 >> 2) & 0xFFFFu));
                if (d0 < SLICE_N) atomicAdd(&bins[d0],  c0);
                if (s0 < SLICE_N) atomicAdd(&bins[s0], -c0);
                if (d1 < SLICE_N) atomicAdd(&bins[d1],  c1);
                if (s1 < SLICE_N) atomicAdd(&bins[s1], -c1);
            }
        }
    }
    __syncthreads();

    float4* pt4 = (float4*)(ws + PART_OFF + (size_t)c * N_NODES + lo);
    for (int j = threadIdx.x; j < SLICE_N / 4; j += 1024)
        pt4[j] = ((const float4*)bins)[j];
}

// ---------------- pass 3: merge partials + squares; LAST block folds final ----------------
__global__ __launch_bounds__(256) void kclfinal_kernel(float* __restrict__ ws,
                                                       float* __restrict__ out)
{
    __shared__ float red[4];
    __shared__ unsigned last;

    const int i = blockIdx.x * blockDim.x + threadIdx.x;
    float acc = 0.f;
    if (i < N_NODES) {
        const float* p = ws + PART_OFF + i;
        float s = 0.f;
        #pragma unroll 8
        for (int c = 0; c < NCHUNK; ++c) s += p[(size_t)c * N_NODES];
        acc = s * s;
    }
    acc = wave_reduce(acc);
    if ((threadIdx.x & 63) == 0) red[threadIdx.x >> 6] = acc;
    __syncthreads();
    if (threadIdx.x == 0) {
        ws[KCLP_OFF + blockIdx.x] = red[0] + red[1] + red[2] + red[3];
        __threadfence();   // KCLP store visible before counter bump
        const unsigned old = atomicAdd((unsigned*)ws + CNT_WORD, 1u);
        last = (old == NKCLB - 1) ? 1u : 0u;
    }
    __syncthreads();
    if (!last) return;

    // ---- final reduction (one block, 256 threads) ----
    __shared__ float red2[4][5];
    float s0 = 0.f, s1 = 0.f, q0 = 0.f, q1 = 0.f, k = 0.f;

    const float4* vp = (const float4*)(ws + VARP_OFF);   // prep output: kernel-boundary safe
    for (int j = threadIdx.x; j < NVARW; j += 256) {
        const float4 v = vp[j];
        s0 += v.x; s1 += v.y; q0 += v.z; q1 += v.w;
    }
    // KCLP written by other blocks this kernel: cross-XCD L2 not coherent ->
    // read via device-scope atomic RMW (+0.0 returns old value).
    for (int j = threadIdx.x; j < NKCLB; j += 256)
        k += unsafeAtomicAdd(ws + KCLP_OFF + j, 0.0f);

    s0 = wave_reduce(s0); s1 = wave_reduce(s1);
    q0 = wave_reduce(q0); q1 = wave_reduce(q1);
    k  = wave_reduce(k);

    const int wid = threadIdx.x >> 6;
    if ((threadIdx.x & 63) == 0) {
        red2[wid][0] = s0; red2[wid][1] = s1; red2[wid][2] = q0;
        red2[wid][3] = q1; red2[wid][4] = k;
    }
    __syncthreads();
    if (threadIdx.x == 0) {
        float a0 = 0.f, a1 = 0.f, a2 = 0.f, a3 = 0.f, a4 = 0.f;
        #pragma unroll
        for (int w = 0; w < 4; ++w) {
            a0 += red2[w][0]; a1 += red2[w][1]; a2 += red2[w][2];
            a3 += red2[w][3]; a4 += red2[w][4];
        }
        const float n    = (float)N_EDGES;
        const float var0 = (a2 - a0 * a0 / n) / (n - 1.0f);
        const float var1 = (a3 - a1 * a1 / n) / (n - 1.0f);
        out[0] = a4 / (float)N_NODES + 0.5f * (var0 + var1);
    }
}

// ---------------- fallback (ws too small): agent-atomic scatter ----------------
#define FB_NODE_OFF 64
__global__ __launch_bounds__(256) void edge_kernel_fb(
    const float*  __restrict__ nf,
    const void*   __restrict__ eidx,
    const float*  __restrict__ logits,
    const float2* __restrict__ params,
    float*        __restrict__ ws)
{
    const int*       i32 = (const int*)eidx;
    const long long* i64 = (const long long*)eidx;
    int any = 0;
    #pragma unroll
    for (int k = 1; k < 32; k += 2) any |= i32[k];
    const bool is32 = (any != 0);

    float* node_sum = ws + FB_NODE_OFF;
    float* acc      = ws + 1;

    float s0 = 0.f, s1 = 0.f, q0 = 0.f, q1 = 0.f;
    const int tid    = blockIdx.x * blockDim.x + threadIdx.x;
    const int stride = gridDim.x * blockDim.x;
    for (int i = tid; i < N_EDGES; i += stride) {
        int src, dst;
        if (is32) { src = i32[i]; dst = i32[N_EDGES + i]; }
        else      { src = (int)i64[i]; dst = (int)i64[N_EDGES + i]; }
        const float2 ep = params[i];
        const float  p  = 1.0f / (1.0f + __expf(-logits[i]));
        const float cur = fabsf(nf[src * 4] - nf[dst * 4]) / (ep.x + ep.y + EPS_F) * p;
        fadd_agent(node_sum + dst,  cur);
        fadd_agent(node_sum + src, -cur);
        s0 += ep.x; s1 += ep.y; q0 += ep.x * ep.x; q1 += ep.y * ep.y;
    }
    s0 = wave_reduce(s0); s1 = wave_reduce(s1);
    q0 = wave_reduce(q0); q1 = wave_reduce(q1);
    if ((threadIdx.x & 63) == 0) {
        fadd_agent(acc + 0, s0); fadd_agent(acc + 1, s1);
        fadd_agent(acc + 2, q0); fadd_agent(acc + 3, q1);
    }
}

__global__ __launch_bounds__(256) void kcl_kernel_fb(float* __restrict__ ws)
{
    const float* node_sum = ws + FB_NODE_OFF;
    float acc = 0.f;
    const int tid    = blockIdx.x * blockDim.x + threadIdx.x;
    const int stride = gridDim.x * blockDim.x;
    for (int i = tid; i < N_NODES; i += stride) {
        const float v = node_sum[i];
        acc += v * v;
    }
    acc = wave_reduce(acc);
    if ((threadIdx.x & 63) == 0) fadd_agent(ws + 5, acc);
}

__global__ void final_kernel_fb(const float* __restrict__ ws, float* __restrict__ out)
{
    const float s0 = ws[1], s1 = ws[2], q0 = ws[3], q1 = ws[4], k = ws[5];
    const float n  = (float)N_EDGES;
    const float var0 = (q0 - s0 * s0 / n) / (n - 1.0f);
    const float var1 = (q1 - s1 * s1 / n) / (n - 1.0f);
    out[0] = k / (float)N_NODES + 0.5f * (var0 + var1);
}

extern "C" void kernel_launch(void* const* d_in, const int* in_sizes, int n_in,
                              void* d_out, int out_size, void* d_ws, size_t ws_size,
                              hipStream_t stream) {
    const float*  nf     = (const float*)d_in[0];
    const void*   eidx   = d_in[1];
    const float*  logits = (const float*)d_in[2];
    const float2* params = (const float2*)d_in[3];
    float* ws  = (float*)d_ws;
    float* out = (float*)d_out;

    const size_t need = (size_t)WS_FLOATS * sizeof(float);   // ~38.7 MB

    if (ws_size >= need) {
        pack_kernel<<<NPACKB, 256, 0, stream>>>(nf, ws);
        prep_kernel<<<GNB, 1024, 0, stream>>>(eidx, logits, params, ws);
        scatter_kernel<<<NCHUNK * NSLICE, 1024, 0, stream>>>(ws);
        kclfinal_kernel<<<NKCLB, 256, 0, stream>>>(ws, out);
    } else {
        hipMemsetAsync(d_ws, 0, 256 + (size_t)N_NODES * sizeof(float), stream);
        edge_kernel_fb<<<2048, 256, 0, stream>>>(nf, eidx, logits, params, ws);
        kcl_kernel_fb<<<200, 256, 0, stream>>>(ws);
        final_kernel_fb<<<1, 1, 0, stream>>>(ws, out);
    }
}